// Round 1
// baseline (320.707 us; speedup 1.0000x reference)
//
#include <hip/hip_runtime.h>
#include <hip/hip_bf16.h>
#include <math.h>

// TemplateColumnWiseAttention, reassociated:
//   q[n,h,:]  = (s[n] @ wq_h) * CH^-1/2        (k_qg, with gate g = sigmoid(s@wg+bg))
//   r[n,h,c]  = sum_ch wk[c, h*64+ch] q[n,h,ch] (k_r)
//   scores    = X r + bias ; a = softmax_t      (k_attn; X[t,c] = t[b,t,n,c])
//   y[n,h,c]  = sum_t a[h,t] X[t,c]             (k_attn, written over r)
//   o[n,hc']  = sum_c y[n,h,c] wv[c,hc']        (k_o)
//   out       = (o * g) @ wo + bo               (k_out)

namespace {

constexpr int Bb = 4, Tt = 32, Nn = 1024, Cc = 256, Hh = 8, CHc = 64;
constexpr int HC = 512;        // H*CH
constexpr int BN = Bb * Nn;    // 4096
constexpr int TILE = 64, BK = 32, LDP = 68;

__device__ __forceinline__ void micro_step(const float (*As)[LDP],
                                           const float (*Bs)[LDP], int tx,
                                           int ty, float acc[4][4]) {
#pragma unroll
  for (int kk = 0; kk < BK; ++kk) {
    const float4 a4 = *(const float4*)&As[kk][ty * 4];
    const float4 b4 = *(const float4*)&Bs[kk][tx * 4];
    const float av[4] = {a4.x, a4.y, a4.z, a4.w};
    const float bv[4] = {b4.x, b4.y, b4.z, b4.w};
#pragma unroll
    for (int i = 0; i < 4; ++i)
#pragma unroll
      for (int j = 0; j < 4; ++j) acc[i][j] = fmaf(av[i], bv[j], acc[i][j]);
  }
}

// ---------- kernel 1: QG = s @ [wq*0.125 | sigmoid(.+bg) of wg] ----------
__global__ __launch_bounds__(256) void k_qg(const float* __restrict__ s,
                                            const float* __restrict__ wq,
                                            const float* __restrict__ wg,
                                            const float* __restrict__ bg,
                                            float* __restrict__ QG) {
  __shared__ float As[BK][LDP];
  __shared__ float Bs[BK][LDP];
  const int rb = blockIdx.x * TILE;
  const int cb = blockIdx.y * TILE;  // [0,1024)
  const bool isq = (cb < HC);
  const float* Bsrc = isq ? (wq + cb) : (wg + (cb - HC));
  const int tid = threadIdx.x, tx = tid & 15, ty = tid >> 4;
  float acc[4][4] = {};
  for (int k0 = 0; k0 < Cc; k0 += BK) {
#pragma unroll
    for (int p = 0; p < 8; ++p) {
      int i = p * 256 + tid;
      int kk = i & 31, r = i >> 5;
      As[kk][r] = s[(size_t)(rb + r) * Cc + k0 + kk];
    }
#pragma unroll
    for (int p = 0; p < 8; ++p) {
      int i = p * 256 + tid;
      int c = i & 63, kk = i >> 6;
      Bs[kk][c] = Bsrc[(size_t)(k0 + kk) * HC + c];
    }
    __syncthreads();
    micro_step(As, Bs, tx, ty, acc);
    __syncthreads();
  }
#pragma unroll
  for (int i = 0; i < 4; ++i) {
    const int r = rb + ty * 4 + i;
    float4 v = make_float4(acc[i][0], acc[i][1], acc[i][2], acc[i][3]);
    if (isq) {
      v.x *= 0.125f; v.y *= 0.125f; v.z *= 0.125f; v.w *= 0.125f;
    } else {
      const int gb = cb - HC + tx * 4;
      v.x = 1.f / (1.f + __expf(-(v.x + bg[gb + 0])));
      v.y = 1.f / (1.f + __expf(-(v.y + bg[gb + 1])));
      v.z = 1.f / (1.f + __expf(-(v.z + bg[gb + 2])));
      v.w = 1.f / (1.f + __expf(-(v.w + bg[gb + 3])));
    }
    *(float4*)&QG[(size_t)r * 1024 + cb + tx * 4] = v;
  }
}

// ---------- kernel 2: r[n, h*256+c] = sum_ch q[n,h*64+ch] wk[c,h*64+ch] ----------
__global__ __launch_bounds__(256) void k_r(const float* __restrict__ QG,
                                           const float* __restrict__ wk,
                                           float* __restrict__ R) {
  __shared__ float As[BK][LDP];
  __shared__ float Bs[BK][LDP];
  const int rb = blockIdx.x * TILE;
  const int cbg = blockIdx.y * TILE;  // [0,2048)
  const int h = cbg >> 8;
  const int cc = cbg & 255;
  const int tid = threadIdx.x, tx = tid & 15, ty = tid >> 4;
  float acc[4][4] = {};
  for (int k0 = 0; k0 < CHc; k0 += BK) {
#pragma unroll
    for (int p = 0; p < 8; ++p) {
      int i = p * 256 + tid;
      int kk = i & 31, r = i >> 5;
      As[kk][r] = QG[(size_t)(rb + r) * 1024 + h * CHc + k0 + kk];
    }
#pragma unroll
    for (int p = 0; p < 8; ++p) {
      int i = p * 256 + tid;
      int kk = i & 31, c = i >> 5;
      Bs[kk][c] = wk[(size_t)(cc + c) * HC + h * CHc + k0 + kk];
    }
    __syncthreads();
    micro_step(As, Bs, tx, ty, acc);
    __syncthreads();
  }
#pragma unroll
  for (int i = 0; i < 4; ++i) {
    const int r = rb + ty * 4 + i;
    float4 v = make_float4(acc[i][0], acc[i][1], acc[i][2], acc[i][3]);
    *(float4*)&R[(size_t)r * 2048 + cbg + tx * 4] = v;
  }
}

// ---------- kernel 3: per-(b,n) scores/softmax/y ----------
__global__ __launch_bounds__(256) void k_attn(const float* __restrict__ tin,
                                              const float* __restrict__ mask,
                                              float* __restrict__ R) {
  __shared__ float X_s[Tt][260];
  __shared__ float r_s[Hh][260];
  __shared__ float a_s[Hh][Tt];
  __shared__ float bias_s[Tt];
  const int ng = blockIdx.x;  // 0..4095
  const int b = ng >> 10;
  const int n = ng & (Nn - 1);
  const int tid = threadIdx.x;

  const float* rrow = R + (size_t)ng * 2048;
#pragma unroll
  for (int p = 0; p < 2; ++p) {
    int i = p * 256 + tid;  // float4 idx [0,512)
    int h = i >> 6, c4 = i & 63;
    *(float4*)&r_s[h][c4 * 4] = *(const float4*)&rrow[(size_t)i * 4];
  }
  const float* tb = tin + ((size_t)b * Tt * Nn + n) * Cc;
#pragma unroll
  for (int p = 0; p < 8; ++p) {
    int i = p * 256 + tid;  // float4 idx [0,2048)
    int tt = i >> 6, c4 = i & 63;
    *(float4*)&X_s[tt][c4 * 4] =
        *(const float4*)&tb[(size_t)tt * Nn * Cc + c4 * 4];
  }
  if (tid < Tt) bias_s[tid] = 1e9f * (mask[b * Tt + tid] - 1.0f);
  __syncthreads();

  {  // scores + softmax (thread = (h, t))
    const int h = tid >> 5, tt = tid & 31;
    float4 acc = make_float4(0.f, 0.f, 0.f, 0.f);
#pragma unroll 8
    for (int i = 0; i < 64; ++i) {
      float4 x = *(const float4*)&X_s[tt][i * 4];
      float4 rv = *(const float4*)&r_s[h][i * 4];
      acc.x = fmaf(x.x, rv.x, acc.x);
      acc.y = fmaf(x.y, rv.y, acc.y);
      acc.z = fmaf(x.z, rv.z, acc.z);
      acc.w = fmaf(x.w, rv.w, acc.w);
    }
    float sc = (acc.x + acc.y) + (acc.z + acc.w) + bias_s[tt];
    float m = sc;
#pragma unroll
    for (int off = 16; off >= 1; off >>= 1) m = fmaxf(m, __shfl_xor(m, off));
    float e = __expf(sc - m);
    float sum = e;
#pragma unroll
    for (int off = 16; off >= 1; off >>= 1) sum += __shfl_xor(sum, off);
    a_s[h][tt] = e / sum;
  }
  __syncthreads();

  {  // y[h,:] = a[h,:] @ X ; overwrite R[ng] (r fully consumed into LDS)
    const int h = tid >> 5, cc = tid & 31;
    float4 acc1 = make_float4(0.f, 0.f, 0.f, 0.f);
    float4 acc2 = make_float4(0.f, 0.f, 0.f, 0.f);
#pragma unroll 8
    for (int tt = 0; tt < Tt; ++tt) {
      const float av = a_s[h][tt];
      float4 x1 = *(const float4*)&X_s[tt][cc * 4];
      float4 x2 = *(const float4*)&X_s[tt][128 + cc * 4];
      acc1.x = fmaf(av, x1.x, acc1.x);
      acc1.y = fmaf(av, x1.y, acc1.y);
      acc1.z = fmaf(av, x1.z, acc1.z);
      acc1.w = fmaf(av, x1.w, acc1.w);
      acc2.x = fmaf(av, x2.x, acc2.x);
      acc2.y = fmaf(av, x2.y, acc2.y);
      acc2.z = fmaf(av, x2.z, acc2.z);
      acc2.w = fmaf(av, x2.w, acc2.w);
    }
    float* yrow = R + (size_t)ng * 2048 + h * 256;
    *(float4*)&yrow[cc * 4] = acc1;
    *(float4*)&yrow[128 + cc * 4] = acc2;
  }
}

// ---------- kernel 4: o[n, h*64+c'] = sum_c y[n,h,c] wv[c, h*64+c'] ----------
__global__ __launch_bounds__(256) void k_o(const float* __restrict__ Y,
                                           const float* __restrict__ wv,
                                           float* __restrict__ O) {
  __shared__ float As[BK][LDP];
  __shared__ float Bs[BK][LDP];
  const int rb = blockIdx.x * TILE;
  const int cbg = blockIdx.y * TILE;  // [0,512), one head per col tile
  const int h = cbg >> 6;
  const int tid = threadIdx.x, tx = tid & 15, ty = tid >> 4;
  float acc[4][4] = {};
  for (int k0 = 0; k0 < Cc; k0 += BK) {
#pragma unroll
    for (int p = 0; p < 8; ++p) {
      int i = p * 256 + tid;
      int kk = i & 31, r = i >> 5;
      As[kk][r] = Y[(size_t)(rb + r) * 2048 + h * 256 + k0 + kk];
    }
#pragma unroll
    for (int p = 0; p < 8; ++p) {
      int i = p * 256 + tid;
      int c = i & 63, kk = i >> 6;
      Bs[kk][c] = wv[(size_t)(k0 + kk) * HC + cbg + c];
    }
    __syncthreads();
    micro_step(As, Bs, tx, ty, acc);
    __syncthreads();
  }
#pragma unroll
  for (int i = 0; i < 4; ++i) {
    const int r = rb + ty * 4 + i;
    float4 v = make_float4(acc[i][0], acc[i][1], acc[i][2], acc[i][3]);
    *(float4*)&O[(size_t)r * HC + cbg + tx * 4] = v;
  }
}

// ---------- kernel 5: out = (o*g) @ wo + bo ----------
__global__ __launch_bounds__(256) void k_out(const float* __restrict__ O,
                                             const float* __restrict__ QG,
                                             const float* __restrict__ wo,
                                             const float* __restrict__ bo,
                                             float* __restrict__ out) {
  __shared__ float As[BK][LDP];
  __shared__ float Bs[BK][LDP];
  const int rb = blockIdx.x * TILE;
  const int cb = blockIdx.y * TILE;  // [0,256)
  const int tid = threadIdx.x, tx = tid & 15, ty = tid >> 4;
  float acc[4][4] = {};
  for (int k0 = 0; k0 < HC; k0 += BK) {  // K = 512
#pragma unroll
    for (int p = 0; p < 8; ++p) {
      int i = p * 256 + tid;
      int kk = i & 31, r = i >> 5;
      const size_t row = (size_t)(rb + r);
      As[kk][r] = O[row * HC + k0 + kk] * QG[row * 1024 + HC + k0 + kk];
    }
#pragma unroll
    for (int p = 0; p < 8; ++p) {
      int i = p * 256 + tid;
      int c = i & 63, kk = i >> 6;
      Bs[kk][c] = wo[(size_t)(k0 + kk) * Cc + cb + c];
    }
    __syncthreads();
    micro_step(As, Bs, tx, ty, acc);
    __syncthreads();
  }
#pragma unroll
  for (int i = 0; i < 4; ++i) {
    const int r = rb + ty * 4 + i;
    const int c = cb + tx * 4;
    float4 v = make_float4(acc[i][0] + bo[c + 0], acc[i][1] + bo[c + 1],
                           acc[i][2] + bo[c + 2], acc[i][3] + bo[c + 3]);
    *(float4*)&out[(size_t)r * Cc + c] = v;
  }
}

}  // namespace

extern "C" void kernel_launch(void* const* d_in, const int* in_sizes, int n_in,
                              void* d_out, int out_size, void* d_ws,
                              size_t ws_size, hipStream_t stream) {
  const float* t = (const float*)d_in[0];
  const float* s = (const float*)d_in[1];
  const float* msk = (const float*)d_in[2];
  const float* wq = (const float*)d_in[3];
  const float* wk = (const float*)d_in[4];
  const float* wv = (const float*)d_in[5];
  const float* wg = (const float*)d_in[6];
  const float* bg = (const float*)d_in[7];
  const float* wo = (const float*)d_in[8];
  const float* bo = (const float*)d_in[9];
  float* out = (float*)d_out;
  float* ws = (float*)d_ws;

  // workspace layout (floats): QG 4096x1024 | R 4096x2048 (r, then y in-place) | O 4096x512
  float* QG = ws;
  float* R = QG + (size_t)BN * 1024;
  float* O = R + (size_t)BN * 2048;
  // total = 4096*(1024+2048+512)*4 B = 58.7 MB

  k_qg<<<dim3(BN / TILE, 1024 / TILE), 256, 0, stream>>>(s, wq, wg, bg, QG);
  k_r<<<dim3(BN / TILE, 2048 / TILE), 256, 0, stream>>>(QG, wk, R);
  k_attn<<<dim3(BN), 256, 0, stream>>>(t, msk, R);
  k_o<<<dim3(BN / TILE, HC / TILE), 256, 0, stream>>>(R, wv, O);
  k_out<<<dim3(BN / TILE, Cc / TILE), 256, 0, stream>>>(O, QG, wo, bo, out);
}

// Round 4
// 257.300 us; speedup vs baseline: 1.2464x; 1.2464x over previous
//
#include <hip/hip_runtime.h>
#include <hip/hip_bf16.h>
#include <math.h>

// Reassociated TemplateColumnWiseAttention (q has a single query row):
//   q = (s@wq)*0.125 ; g = sigmoid(s@wg+bg)          (k_qg, bf16 MFMA)
//   r[n,h,c] = sum_ch q[n,h,ch] wk[c,h*64+ch]        (k_r, bf16 MFMA)
//   scores[h,t] = X[t,:]·r[h,:] + bias ; softmax_t   (k_attn, VALU, X bf16 in LDS)
//   y[h,c] = sum_t a[h,t] X[t,c]                     (k_attn, bf16 out)
//   o = y @ wv_h                                     (k_o, bf16 MFMA)
//   out = (o*g) @ wo + bo                            (k_out, bf16 MFMA)

namespace {

constexpr int Nn = 1024, Cc = 256;
constexpr int BN = 4096;  // B*N rows

typedef __bf16 bf16x8 __attribute__((ext_vector_type(8)));
typedef __bf16 bf16x4 __attribute__((ext_vector_type(4)));
typedef float vf4 __attribute__((ext_vector_type(4)));

__device__ __forceinline__ __bf16 f2b(float f) { return (__bf16)f; }

// ---------------- conversion / transpose kernel ----------------
// grid 1664: [0,1024) s copy; [1024,1152) wk copy; then 4x128 transposes.
template <int SK, int SN>
__device__ __forceinline__ void transpose_tile(const float* __restrict__ src,
                                               __bf16* __restrict__ dst,
                                               float (*T)[33], int tloc,
                                               int tid) {
  constexpr int ntn = SN / 32;
  const int tkb = tloc / ntn, tnb = tloc % ntn;
  const int row = tid >> 3, c4 = tid & 7;
  float4 v = *(const float4*)&src[(size_t)(tkb * 32 + row) * SN + tnb * 32 + c4 * 4];
  T[row][c4 * 4 + 0] = v.x;
  T[row][c4 * 4 + 1] = v.y;
  T[row][c4 * 4 + 2] = v.z;
  T[row][c4 * 4 + 3] = v.w;
  __syncthreads();
  const int nr = tid >> 3, k4 = tid & 7;
  bf16x4 o;
#pragma unroll
  for (int q = 0; q < 4; ++q) o[q] = f2b(T[k4 * 4 + q][nr]);
  *(bf16x4*)&dst[(size_t)(tnb * 32 + nr) * SK + tkb * 32 + k4 * 4] = o;
}

__global__ __launch_bounds__(256) void k_cvt(
    const float* __restrict__ s, const float* __restrict__ wq,
    const float* __restrict__ wg, const float* __restrict__ wk,
    const float* __restrict__ wv, const float* __restrict__ wo,
    __bf16* __restrict__ sbf, __bf16* __restrict__ wqT,
    __bf16* __restrict__ wgT, __bf16* __restrict__ wkbf,
    __bf16* __restrict__ wvT, __bf16* __restrict__ woT) {
  __shared__ float T[32][33];
  const int bid = blockIdx.x, tid = threadIdx.x;
  if (bid < 1024) {
    size_t i = (size_t)bid * 1024 + tid * 4;
    float4 v = *(const float4*)&s[i];
    bf16x4 o = {f2b(v.x), f2b(v.y), f2b(v.z), f2b(v.w)};
    *(bf16x4*)&sbf[i] = o;
  } else if (bid < 1152) {
    size_t i = (size_t)(bid - 1024) * 1024 + tid * 4;
    float4 v = *(const float4*)&wk[i];
    bf16x4 o = {f2b(v.x), f2b(v.y), f2b(v.z), f2b(v.w)};
    *(bf16x4*)&wkbf[i] = o;
  } else if (bid < 1280) {
    transpose_tile<256, 512>(wq, wqT, T, bid - 1152, tid);
  } else if (bid < 1408) {
    transpose_tile<256, 512>(wg, wgT, T, bid - 1280, tid);
  } else if (bid < 1536) {
    transpose_tile<256, 512>(wv, wvT, T, bid - 1408, tid);
  } else {
    transpose_tile<512, 256>(wo, woT, T, bid - 1536, tid);
  }
}

// ---------------- MFMA tile core (64x64 tile, 4 waves 2x2, BK=32) ----------
__device__ __forceinline__ void mfma_tile(const __bf16 (*Al)[40],
                                          const __bf16 (*Bl)[40], int lane,
                                          int wm, int wn, vf4 acc[2][2]) {
  const int kg = lane >> 4, lr = lane & 15;
  bf16x8 a0 = *(const bf16x8*)&Al[wm * 32 + lr][kg * 8];
  bf16x8 a1 = *(const bf16x8*)&Al[wm * 32 + 16 + lr][kg * 8];
  bf16x8 b0 = *(const bf16x8*)&Bl[wn * 32 + lr][kg * 8];
  bf16x8 b1 = *(const bf16x8*)&Bl[wn * 32 + 16 + lr][kg * 8];
  acc[0][0] = __builtin_amdgcn_mfma_f32_16x16x32_bf16(a0, b0, acc[0][0], 0, 0, 0);
  acc[0][1] = __builtin_amdgcn_mfma_f32_16x16x32_bf16(a0, b1, acc[0][1], 0, 0, 0);
  acc[1][0] = __builtin_amdgcn_mfma_f32_16x16x32_bf16(a1, b0, acc[1][0], 0, 0, 0);
  acc[1][1] = __builtin_amdgcn_mfma_f32_16x16x32_bf16(a1, b1, acc[1][1], 0, 0, 0);
}

// ---------------- k_qg: [Q|G] = s @ [wq*0.125 | sigmoid(wg)+bg] ------------
__global__ __launch_bounds__(256) void k_qg(const __bf16* __restrict__ sbf,
                                            const __bf16* __restrict__ wqT,
                                            const __bf16* __restrict__ wgT,
                                            const float* __restrict__ bg,
                                            __bf16* __restrict__ Qbf,
                                            float* __restrict__ G) {
  __shared__ __bf16 Al[64][40], Bl[64][40];
  const int tid = threadIdx.x, lane = tid & 63, w = tid >> 6;
  const int wm = w >> 1, wn = w & 1;
  const int rb = blockIdx.x * 64, by = blockIdx.y;
  const __bf16* Bsrc =
      (by < 8) ? wqT + (size_t)(by * 64) * 256 : wgT + (size_t)((by - 8) * 64) * 256;
  vf4 acc[2][2] = {};
  const int srow = tid >> 2, skg = tid & 3;
  for (int k0 = 0; k0 < 256; k0 += 32) {
    *(bf16x8*)&Al[srow][skg * 8] =
        *(const bf16x8*)&sbf[(size_t)(rb + srow) * 256 + k0 + skg * 8];
    *(bf16x8*)&Bl[srow][skg * 8] =
        *(const bf16x8*)&Bsrc[(size_t)srow * 256 + k0 + skg * 8];
    __syncthreads();
    mfma_tile(Al, Bl, lane, wm, wn, acc);
    __syncthreads();
  }
  const int r4 = (lane >> 4) * 4, cl = lane & 15;
#pragma unroll
  for (int mi = 0; mi < 2; ++mi)
#pragma unroll
    for (int ni = 0; ni < 2; ++ni) {
      vf4 v = acc[mi][ni];
#pragma unroll
      for (int j = 0; j < 4; ++j) {
        int row = rb + wm * 32 + mi * 16 + r4 + j;
        int col = by * 64 + wn * 32 + ni * 16 + cl;
        if (by < 8) {
          Qbf[(size_t)row * 512 + col] = f2b(v[j] * 0.125f);
        } else {
          int c = col - 512;
          G[(size_t)row * 512 + c] = 1.f / (1.f + __expf(-(v[j] + bg[c])));
        }
      }
    }
}

// ---------------- k_r: r[n, h*256+c] = q[n,h,:]·wk[c, h*64+:] --------------
__global__ __launch_bounds__(256) void k_r(const __bf16* __restrict__ Qbf,
                                           const __bf16* __restrict__ wkbf,
                                           float* __restrict__ R) {
  __shared__ __bf16 Al[64][40], Bl[64][40];
  const int tid = threadIdx.x, lane = tid & 63, w = tid >> 6;
  const int wm = w >> 1, wn = w & 1;
  const int rb = blockIdx.x * 64, by = blockIdx.y;
  const int h = by >> 2, ct = by & 3;
  vf4 acc[2][2] = {};
  const int srow = tid >> 2, skg = tid & 3;
  for (int k0 = 0; k0 < 64; k0 += 32) {
    *(bf16x8*)&Al[srow][skg * 8] =
        *(const bf16x8*)&Qbf[(size_t)(rb + srow) * 512 + h * 64 + k0 + skg * 8];
    *(bf16x8*)&Bl[srow][skg * 8] =
        *(const bf16x8*)&wkbf[(size_t)(ct * 64 + srow) * 512 + h * 64 + k0 + skg * 8];
    __syncthreads();
    mfma_tile(Al, Bl, lane, wm, wn, acc);
    __syncthreads();
  }
  const int r4 = (lane >> 4) * 4, cl = lane & 15;
#pragma unroll
  for (int mi = 0; mi < 2; ++mi)
#pragma unroll
    for (int ni = 0; ni < 2; ++ni) {
      vf4 v = acc[mi][ni];
#pragma unroll
      for (int j = 0; j < 4; ++j) {
        int row = rb + wm * 32 + mi * 16 + r4 + j;
        int col = h * 256 + ct * 64 + wn * 32 + ni * 16 + cl;
        R[(size_t)row * 2048 + col] = v[j];
      }
    }
}

// ---------------- k_attn: scores + softmax + y (per b,n) -------------------
__global__ __launch_bounds__(256) void k_attn(const float* __restrict__ tin,
                                              const float* __restrict__ mask,
                                              const float* __restrict__ R,
                                              __bf16* __restrict__ Y) {
  __shared__ __bf16 Xb[32][264];
  __shared__ float r_s[8][260];
  __shared__ float a_s[8][32];
  __shared__ float bias_s[32];
  const int ng = blockIdx.x;  // b*1024 + n
  const int b = ng >> 10, n = ng & (Nn - 1);
  const int tid = threadIdx.x;

  const float* rrow = R + (size_t)ng * 2048;
#pragma unroll
  for (int p = 0; p < 2; ++p) {
    int i = p * 256 + tid;  // float4 idx [0,512)
    *(float4*)&r_s[i >> 6][(i & 63) * 4] = *(const float4*)&rrow[(size_t)i * 4];
  }
  const float* tb = tin + ((size_t)b * 32 * Nn + n) * Cc;
#pragma unroll
  for (int p = 0; p < 8; ++p) {
    int i = p * 256 + tid;  // float4 idx [0,2048)
    int tt = i >> 6, c4 = i & 63;
    float4 v = *(const float4*)&tb[(size_t)tt * Nn * Cc + c4 * 4];
    bf16x4 o = {f2b(v.x), f2b(v.y), f2b(v.z), f2b(v.w)};
    *(bf16x4*)&Xb[tt][c4 * 4] = o;
  }
  if (tid < 32) bias_s[tid] = 1e9f * (mask[b * 32 + tid] - 1.0f);
  __syncthreads();

  {  // scores + softmax; thread = (h = tid>>5, t = tid&31)
    const int tt = tid & 31, hh = tid >> 5;
    float av[8] = {};
#pragma unroll 4
    for (int kk = 0; kk < 32; ++kk) {
      bf16x8 xv = *(const bf16x8*)&Xb[tt][kk * 8];
      float4 r1 = *(const float4*)&r_s[hh][kk * 8];
      float4 r2 = *(const float4*)&r_s[hh][kk * 8 + 4];
      av[0] = fmaf((float)xv[0], r1.x, av[0]);
      av[1] = fmaf((float)xv[1], r1.y, av[1]);
      av[2] = fmaf((float)xv[2], r1.z, av[2]);
      av[3] = fmaf((float)xv[3], r1.w, av[3]);
      av[4] = fmaf((float)xv[4], r2.x, av[4]);
      av[5] = fmaf((float)xv[5], r2.y, av[5]);
      av[6] = fmaf((float)xv[6], r2.z, av[6]);
      av[7] = fmaf((float)xv[7], r2.w, av[7]);
    }
    float sc = ((av[0] + av[1]) + (av[2] + av[3])) +
               ((av[4] + av[5]) + (av[6] + av[7])) + bias_s[tt];
    float m = sc;
#pragma unroll
    for (int off = 16; off >= 1; off >>= 1) m = fmaxf(m, __shfl_xor(m, off));
    float e = __expf(sc - m);
    float sum = e;
#pragma unroll
    for (int off = 16; off >= 1; off >>= 1) sum += __shfl_xor(sum, off);
    a_s[hh][tt] = e / sum;
  }
  __syncthreads();

  {  // y[h, cc*8 .. +7] ; thread = (h = tid>>5, cc = tid&31)
    const int cc = tid & 31, hh = tid >> 5;
    float acc[8] = {};
#pragma unroll 8
    for (int tt = 0; tt < 32; ++tt) {
      const float a = a_s[hh][tt];
      bf16x8 xv = *(const bf16x8*)&Xb[tt][cc * 8];
#pragma unroll
      for (int j = 0; j < 8; ++j) acc[j] = fmaf(a, (float)xv[j], acc[j]);
    }
    bf16x8 o;
#pragma unroll
    for (int j = 0; j < 8; ++j) o[j] = f2b(acc[j]);
    *(bf16x8*)&Y[(size_t)ng * 2048 + hh * 256 + cc * 8] = o;
  }
}

// ---------------- k_o: o[n, h*64+c'] = y[n,h,:] @ wv[:, h*64+c'] -----------
__global__ __launch_bounds__(256) void k_o(const __bf16* __restrict__ Ybf,
                                           const __bf16* __restrict__ wvT,
                                           float* __restrict__ O) {
  __shared__ __bf16 Al[64][40], Bl[64][40];
  const int tid = threadIdx.x, lane = tid & 63, w = tid >> 6;
  const int wm = w >> 1, wn = w & 1;
  const int rb = blockIdx.x * 64, h = blockIdx.y;
  vf4 acc[2][2] = {};
  const int srow = tid >> 2, skg = tid & 3;
  for (int k0 = 0; k0 < 256; k0 += 32) {
    *(bf16x8*)&Al[srow][skg * 8] =
        *(const bf16x8*)&Ybf[(size_t)(rb + srow) * 2048 + h * 256 + k0 + skg * 8];
    *(bf16x8*)&Bl[srow][skg * 8] =
        *(const bf16x8*)&wvT[(size_t)(h * 64 + srow) * 256 + k0 + skg * 8];
    __syncthreads();
    mfma_tile(Al, Bl, lane, wm, wn, acc);
    __syncthreads();
  }
  const int r4 = (lane >> 4) * 4, cl = lane & 15;
#pragma unroll
  for (int mi = 0; mi < 2; ++mi)
#pragma unroll
    for (int ni = 0; ni < 2; ++ni) {
      vf4 v = acc[mi][ni];
#pragma unroll
      for (int j = 0; j < 4; ++j) {
        int row = rb + wm * 32 + mi * 16 + r4 + j;
        int col = h * 64 + wn * 32 + ni * 16 + cl;
        O[(size_t)row * 512 + col] = v[j];
      }
    }
}

// ---------------- k_out: out = (o*g) @ wo + bo -----------------------------
__global__ __launch_bounds__(256) void k_out(const float* __restrict__ O,
                                             const float* __restrict__ G,
                                             const __bf16* __restrict__ woT,
                                             const float* __restrict__ bo,
                                             float* __restrict__ out) {
  __shared__ __bf16 Al[64][40], Bl[64][40];
  const int tid = threadIdx.x, lane = tid & 63, w = tid >> 6;
  const int wm = w >> 1, wn = w & 1;
  const int rb = blockIdx.x * 64, by = blockIdx.y;
  vf4 acc[2][2] = {};
  const int srow = tid >> 2, skg = tid & 3;
  for (int k0 = 0; k0 < 512; k0 += 32) {
    {
      size_t base = (size_t)(rb + srow) * 512 + k0 + skg * 8;
      float4 o1 = *(const float4*)&O[base];
      float4 o2 = *(const float4*)&O[base + 4];
      float4 g1 = *(const float4*)&G[base];
      float4 g2 = *(const float4*)&G[base + 4];
      bf16x8 a;
      a[0] = f2b(o1.x * g1.x);
      a[1] = f2b(o1.y * g1.y);
      a[2] = f2b(o1.z * g1.z);
      a[3] = f2b(o1.w * g1.w);
      a[4] = f2b(o2.x * g2.x);
      a[5] = f2b(o2.y * g2.y);
      a[6] = f2b(o2.z * g2.z);
      a[7] = f2b(o2.w * g2.w);
      *(bf16x8*)&Al[srow][skg * 8] = a;
    }
    *(bf16x8*)&Bl[srow][skg * 8] =
        *(const bf16x8*)&woT[(size_t)(by * 64 + srow) * 512 + k0 + skg * 8];
    __syncthreads();
    mfma_tile(Al, Bl, lane, wm, wn, acc);
    __syncthreads();
  }
  const int r4 = (lane >> 4) * 4, cl = lane & 15;
#pragma unroll
  for (int mi = 0; mi < 2; ++mi)
#pragma unroll
    for (int ni = 0; ni < 2; ++ni) {
      vf4 v = acc[mi][ni];
#pragma unroll
      for (int j = 0; j < 4; ++j) {
        int row = rb + wm * 32 + mi * 16 + r4 + j;
        int col = by * 64 + wn * 32 + ni * 16 + cl;
        out[(size_t)row * 256 + col] = v[j] + bo[col];
      }
    }
}

}  // namespace

extern "C" void kernel_launch(void* const* d_in, const int* in_sizes, int n_in,
                              void* d_out, int out_size, void* d_ws,
                              size_t ws_size, hipStream_t stream) {
  const float* t = (const float*)d_in[0];
  const float* s = (const float*)d_in[1];
  const float* msk = (const float*)d_in[2];
  const float* wq = (const float*)d_in[3];
  const float* wk = (const float*)d_in[4];
  const float* wv = (const float*)d_in[5];
  const float* wg = (const float*)d_in[6];
  const float* bg = (const float*)d_in[7];
  const float* wo = (const float*)d_in[8];
  const float* bo = (const float*)d_in[9];
  float* out = (float*)d_out;

  // workspace carve (all sizes 256B-aligned)
  char* p = (char*)d_ws;
  __bf16* Qbf = (__bf16*)p;              p += (size_t)BN * 512 * 2;    // 4 MB
  float* G = (float*)p;                  p += (size_t)BN * 512 * 4;    // 8 MB
  float* R = (float*)p;                  p += (size_t)BN * 2048 * 4;   // 32 MB
  __bf16* Ybf = (__bf16*)p;              p += (size_t)BN * 2048 * 2;   // 16 MB
  float* O = (float*)p;                  p += (size_t)BN * 512 * 4;    // 8 MB
  __bf16* sbf = (__bf16*)p;              p += (size_t)BN * 256 * 2;    // 2 MB
  __bf16* wqT = (__bf16*)p;              p += 512 * 256 * 2;
  __bf16* wgT = (__bf16*)p;              p += 512 * 256 * 2;
  __bf16* wvT = (__bf16*)p;              p += 512 * 256 * 2;
  __bf16* woT = (__bf16*)p;              p += 256 * 512 * 2;
  __bf16* wkbf = (__bf16*)p;             p += 256 * 512 * 2;

  k_cvt<<<1664, 256, 0, stream>>>(s, wq, wg, wk, wv, wo, sbf, wqT, wgT, wkbf,
                                  wvT, woT);
  k_qg<<<dim3(BN / 64, 16), 256, 0, stream>>>(sbf, wqT, wgT, bg, Qbf, G);
  k_r<<<dim3(BN / 64, 32), 256, 0, stream>>>(Qbf, wkbf, R);
  k_attn<<<dim3(BN), 256, 0, stream>>>(t, msk, R, Ybf);
  k_o<<<dim3(BN / 64, 8), 256, 0, stream>>>(Ybf, wvT, O);
  k_out<<<dim3(BN / 64, 4), 256, 0, stream>>>(O, G, woT, bo, out);
}

// Round 5
// 256.287 us; speedup vs baseline: 1.2514x; 1.0040x over previous
//
#include <hip/hip_runtime.h>
#include <hip/hip_bf16.h>
#include <math.h>

// Reassociated TemplateColumnWiseAttention (single query row):
//   k_cvtW : weight transposes/converts (wqT,wgT,wvT,woT,wkbf) bf16
//   k_qg   : q = (s@wq)*0.125 -> Qbf ; g = sigmoid(s@wg+bg) -> Gbf   (MFMA)
//   k_r    : r[n,h,c] = sum_ch q[n,h,ch] wk[c,h*64+ch] -> Rbf        (MFMA)
//   k_main : per (b, 16-n tile) resident block:
//              scores = X r + bias (MFMA, wave0) ; softmax (in-reg)
//              y = a^T X (VALU, wave=head, overwrites r in LDS)
//              o = y @ wvT  (MFMA, B-frags direct from L2)
//              out = (o*g) @ woT + bo (MFMA, direct store)

namespace {

constexpr int BN = 4096;  // B*N rows

typedef __bf16 bf16x8 __attribute__((ext_vector_type(8)));
typedef __bf16 bf16x4 __attribute__((ext_vector_type(4)));
typedef float vf4 __attribute__((ext_vector_type(4)));

__device__ __forceinline__ __bf16 f2b(float f) { return (__bf16)f; }

// ---------------- weight conversion / transpose ----------------
template <int SK, int SN>
__device__ __forceinline__ void transpose_tile(const float* __restrict__ src,
                                               __bf16* __restrict__ dst,
                                               float (*T)[33], int tloc,
                                               int tid) {
  constexpr int ntn = SN / 32;
  const int tkb = tloc / ntn, tnb = tloc % ntn;
  const int row = tid >> 3, c4 = tid & 7;
  float4 v = *(const float4*)&src[(size_t)(tkb * 32 + row) * SN + tnb * 32 + c4 * 4];
  T[row][c4 * 4 + 0] = v.x;
  T[row][c4 * 4 + 1] = v.y;
  T[row][c4 * 4 + 2] = v.z;
  T[row][c4 * 4 + 3] = v.w;
  __syncthreads();
  const int nr = tid >> 3, k4 = tid & 7;
  bf16x4 o;
#pragma unroll
  for (int q = 0; q < 4; ++q) o[q] = f2b(T[k4 * 4 + q][nr]);
  *(bf16x4*)&dst[(size_t)(tnb * 32 + nr) * SK + tkb * 32 + k4 * 4] = o;
}

__global__ __launch_bounds__(256) void k_cvtW(
    const float* __restrict__ wq, const float* __restrict__ wg,
    const float* __restrict__ wk, const float* __restrict__ wv,
    const float* __restrict__ wo, __bf16* __restrict__ wqT,
    __bf16* __restrict__ wgT, __bf16* __restrict__ wkbf,
    __bf16* __restrict__ wvT, __bf16* __restrict__ woT) {
  __shared__ float T[32][33];
  const int bid = blockIdx.x, tid = threadIdx.x;
  if (bid < 128) {  // wk convert (no transpose)
    size_t i = (size_t)bid * 1024 + tid * 4;
    float4 v = *(const float4*)&wk[i];
    bf16x4 o = {f2b(v.x), f2b(v.y), f2b(v.z), f2b(v.w)};
    *(bf16x4*)&wkbf[i] = o;
  } else if (bid < 256) {
    transpose_tile<256, 512>(wq, wqT, T, bid - 128, tid);
  } else if (bid < 384) {
    transpose_tile<256, 512>(wg, wgT, T, bid - 256, tid);
  } else if (bid < 512) {
    transpose_tile<256, 512>(wv, wvT, T, bid - 384, tid);
  } else {
    transpose_tile<512, 256>(wo, woT, T, bid - 512, tid);
  }
}

// ---------------- MFMA tile core (64x64 tile, 4 waves 2x2, BK=32) ----------
__device__ __forceinline__ void mfma_tile(const __bf16 (*Al)[40],
                                          const __bf16 (*Bl)[40], int lane,
                                          int wm, int wn, vf4 acc[2][2]) {
  const int kg = lane >> 4, lr = lane & 15;
  bf16x8 a0 = *(const bf16x8*)&Al[wm * 32 + lr][kg * 8];
  bf16x8 a1 = *(const bf16x8*)&Al[wm * 32 + 16 + lr][kg * 8];
  bf16x8 b0 = *(const bf16x8*)&Bl[wn * 32 + lr][kg * 8];
  bf16x8 b1 = *(const bf16x8*)&Bl[wn * 32 + 16 + lr][kg * 8];
  acc[0][0] = __builtin_amdgcn_mfma_f32_16x16x32_bf16(a0, b0, acc[0][0], 0, 0, 0);
  acc[0][1] = __builtin_amdgcn_mfma_f32_16x16x32_bf16(a0, b1, acc[0][1], 0, 0, 0);
  acc[1][0] = __builtin_amdgcn_mfma_f32_16x16x32_bf16(a1, b0, acc[1][0], 0, 0, 0);
  acc[1][1] = __builtin_amdgcn_mfma_f32_16x16x32_bf16(a1, b1, acc[1][1], 0, 0, 0);
}

// ---------------- k_qg: Qbf = (s@wq)*.125 ; Gbf = sigmoid(s@wg+bg) ---------
__global__ __launch_bounds__(256) void k_qg(const float* __restrict__ s,
                                            const __bf16* __restrict__ wqT,
                                            const __bf16* __restrict__ wgT,
                                            const float* __restrict__ bg,
                                            __bf16* __restrict__ Qbf,
                                            __bf16* __restrict__ Gbf) {
  __shared__ __bf16 Al[64][40], Bl[64][40];
  const int tid = threadIdx.x, lane = tid & 63, w = tid >> 6;
  const int wm = w >> 1, wn = w & 1;
  const int rb = blockIdx.x * 64, by = blockIdx.y;
  const __bf16* Bsrc =
      (by < 8) ? wqT + (size_t)(by * 64) * 256 : wgT + (size_t)((by - 8) * 64) * 256;
  vf4 acc[2][2] = {};
  const int srow = tid >> 2, skg = tid & 3;
  for (int k0 = 0; k0 < 256; k0 += 32) {
    {
      const float* sp = &s[(size_t)(rb + srow) * 256 + k0 + skg * 8];
      float4 v1 = *(const float4*)sp;
      float4 v2 = *(const float4*)(sp + 4);
      bf16x8 a = {f2b(v1.x), f2b(v1.y), f2b(v1.z), f2b(v1.w),
                  f2b(v2.x), f2b(v2.y), f2b(v2.z), f2b(v2.w)};
      *(bf16x8*)&Al[srow][skg * 8] = a;
    }
    *(bf16x8*)&Bl[srow][skg * 8] =
        *(const bf16x8*)&Bsrc[(size_t)srow * 256 + k0 + skg * 8];
    __syncthreads();
    mfma_tile(Al, Bl, lane, wm, wn, acc);
    __syncthreads();
  }
  const int r4 = (lane >> 4) * 4, cl = lane & 15;
#pragma unroll
  for (int mi = 0; mi < 2; ++mi)
#pragma unroll
    for (int ni = 0; ni < 2; ++ni) {
      vf4 v = acc[mi][ni];
#pragma unroll
      for (int j = 0; j < 4; ++j) {
        int row = rb + wm * 32 + mi * 16 + r4 + j;
        int col = by * 64 + wn * 32 + ni * 16 + cl;
        if (by < 8) {
          Qbf[(size_t)row * 512 + col] = f2b(v[j] * 0.125f);
        } else {
          int c = col - 512;
          Gbf[(size_t)row * 512 + c] =
              f2b(1.f / (1.f + __expf(-(v[j] + bg[c]))));
        }
      }
    }
}

// ---------------- k_r: Rbf[n, h*256+c] = q[n,h,:]·wk[c, h*64+:] ------------
__global__ __launch_bounds__(256) void k_r(const __bf16* __restrict__ Qbf,
                                           const __bf16* __restrict__ wkbf,
                                           __bf16* __restrict__ Rbf) {
  __shared__ __bf16 Al[64][40], Bl[64][40];
  const int tid = threadIdx.x, lane = tid & 63, w = tid >> 6;
  const int wm = w >> 1, wn = w & 1;
  const int rb = blockIdx.x * 64, by = blockIdx.y;
  const int h = by >> 2, ct = by & 3;
  vf4 acc[2][2] = {};
  const int srow = tid >> 2, skg = tid & 3;
  for (int k0 = 0; k0 < 64; k0 += 32) {
    *(bf16x8*)&Al[srow][skg * 8] =
        *(const bf16x8*)&Qbf[(size_t)(rb + srow) * 512 + h * 64 + k0 + skg * 8];
    *(bf16x8*)&Bl[srow][skg * 8] =
        *(const bf16x8*)&wkbf[(size_t)(ct * 64 + srow) * 512 + h * 64 + k0 + skg * 8];
    __syncthreads();
    mfma_tile(Al, Bl, lane, wm, wn, acc);
    __syncthreads();
  }
  const int r4 = (lane >> 4) * 4, cl = lane & 15;
#pragma unroll
  for (int mi = 0; mi < 2; ++mi)
#pragma unroll
    for (int ni = 0; ni < 2; ++ni) {
      vf4 v = acc[mi][ni];
#pragma unroll
      for (int j = 0; j < 4; ++j) {
        int row = rb + wm * 32 + mi * 16 + r4 + j;
        int col = h * 256 + ct * 64 + wn * 32 + ni * 16 + cl;
        Rbf[(size_t)row * 2048 + col] = f2b(v[j]);
      }
    }
}

// ---------------- k_main: fused attn + o + gate + out ----------------------
// grid = 256 blocks (b x 64 n-tiles of 16), 512 threads (8 waves), 1 block/CU.
constexpr int RY_N = 2136;  // per-n stride (elems): 8*264 + 24 pad, 16B-aligned
constexpr int RY_H = 264;   // per-head stride

__global__ __launch_bounds__(512, 1) void k_main(
    const float* __restrict__ tin, const float* __restrict__ mask,
    const __bf16* __restrict__ Rbf, const __bf16* __restrict__ Gbf,
    const __bf16* __restrict__ wvT, const __bf16* __restrict__ woT,
    const float* __restrict__ bo, float* __restrict__ out) {
  __shared__ __bf16 rY[16 * RY_N];    // r, overwritten by y   (68.3 KB)
  __shared__ __bf16 Xb[2][32][264];   // X double buffer       (33.8 KB)
  __shared__ __bf16 gS[16][520];      // gate                  (16.6 KB)
  __shared__ __bf16 oS[16][536];      // o*g                   (17.2 KB)
  __shared__ float aS[8][36];         // attention weights
  __shared__ float biasS[32];

  const int tid = threadIdx.x, lane = tid & 63, wid = tid >> 6;
  const int b = blockIdx.x >> 6;
  const int n0 = (blockIdx.x & 63) * 16;
  const int bn0 = b * 1024 + n0;

  // ---- phase 0: stage r, g, bias, X_0 ----
#pragma unroll
  for (int p = 0; p < 8; ++p) {
    int q = p * 512 + tid;  // 4096 bf16x8 chunks
    int n = q >> 8, rem = q & 255;
    *(bf16x8*)&rY[n * RY_N + (rem >> 5) * RY_H + (rem & 31) * 8] =
        *(const bf16x8*)&Rbf[(size_t)(bn0 + n) * 2048 + rem * 8];
  }
#pragma unroll
  for (int p = 0; p < 2; ++p) {
    int q = p * 512 + tid;  // 1024 chunks
    int n = q >> 6, c8 = q & 63;
    *(bf16x8*)&gS[n][c8 * 8] =
        *(const bf16x8*)&Gbf[(size_t)(bn0 + n) * 512 + c8 * 8];
  }
  if (tid < 32) biasS[tid] = 1e9f * (mask[b * 32 + tid] - 1.0f);
  {  // X_0
    const size_t base = (size_t)b * 8388608 + (size_t)(n0)*256;
#pragma unroll
    for (int p = 0; p < 4; ++p) {
      int i = p * 512 + tid;
      int tt = i >> 6, c4 = i & 63;
      float4 v = *(const float4*)&tin[base + (size_t)tt * 262144 + c4 * 4];
      bf16x4 o4 = {f2b(v.x), f2b(v.y), f2b(v.z), f2b(v.w)};
      *(bf16x4*)&Xb[0][tt][c4 * 4] = o4;
    }
  }
  __syncthreads();

  // ---- phase 1: per-n {scores, softmax, PV} with X prefetch ----
  for (int n = 0; n < 16; ++n) {
    const int cur = n & 1;
    float4 xr[4];
    if (n < 15) {  // issue X_{n+1} loads (consumed after softmax barrier)
      const size_t base = (size_t)b * 8388608 + (size_t)(n0 + n + 1) * 256;
#pragma unroll
      for (int p = 0; p < 4; ++p) {
        int i = p * 512 + tid;
        xr[p] = *(const float4*)&tin[base + (size_t)(i >> 6) * 262144 + (i & 63) * 4];
      }
    }
    if (wid == 0) {  // scores: M=32(t) x N=16(8h) x K=256  (2 MFMA tiles x 8k)
      vf4 d0 = {0.f, 0.f, 0.f, 0.f}, d1 = {0.f, 0.f, 0.f, 0.f};
      const int hh = lane & 7, kg = lane >> 4;
#pragma unroll
      for (int k8 = 0; k8 < 8; ++k8) {
        bf16x8 bfr = *(const bf16x8*)&rY[n * RY_N + hh * RY_H + k8 * 32 + kg * 8];
        bf16x8 a0 = *(const bf16x8*)&Xb[cur][lane & 15][k8 * 32 + kg * 8];
        bf16x8 a1 = *(const bf16x8*)&Xb[cur][16 + (lane & 15)][k8 * 32 + kg * 8];
        d0 = __builtin_amdgcn_mfma_f32_16x16x32_bf16(a0, bfr, d0, 0, 0, 0);
        d1 = __builtin_amdgcn_mfma_f32_16x16x32_bf16(a1, bfr, d1, 0, 0, 0);
      }
      float sc[8];
#pragma unroll
      for (int j = 0; j < 4; ++j) {
        int t = (lane >> 4) * 4 + j;
        sc[j] = d0[j] + biasS[t];
        sc[4 + j] = d1[j] + biasS[16 + t];
      }
      float m = sc[0];
#pragma unroll
      for (int j = 1; j < 8; ++j) m = fmaxf(m, sc[j]);
      m = fmaxf(m, __shfl_xor(m, 16));
      m = fmaxf(m, __shfl_xor(m, 32));
      float e[8], sum = 0.f;
#pragma unroll
      for (int j = 0; j < 8; ++j) {
        e[j] = __expf(sc[j] - m);
        sum += e[j];
      }
      sum += __shfl_xor(sum, 16);
      sum += __shfl_xor(sum, 32);
      const float rs = 1.f / sum;
      if ((lane & 15) < 8) {
        const int h = lane & 15;
#pragma unroll
        for (int j = 0; j < 4; ++j) {
          aS[h][(lane >> 4) * 4 + j] = e[j] * rs;
          aS[h][16 + (lane >> 4) * 4 + j] = e[4 + j] * rs;
        }
      }
    }
    __syncthreads();  // aS ready; scores done reading rY[n]

    {  // PV: wave = head; y[h][lane*4..+3] overwrites rY[n]
      float acc0 = 0.f, acc1 = 0.f, acc2 = 0.f, acc3 = 0.f;
#pragma unroll
      for (int tt = 0; tt < 32; ++tt) {
        const float a = aS[wid][tt];
        bf16x4 xv = *(const bf16x4*)&Xb[cur][tt][lane * 4];
        acc0 = fmaf(a, (float)xv[0], acc0);
        acc1 = fmaf(a, (float)xv[1], acc1);
        acc2 = fmaf(a, (float)xv[2], acc2);
        acc3 = fmaf(a, (float)xv[3], acc3);
      }
      bf16x4 y4 = {f2b(acc0), f2b(acc1), f2b(acc2), f2b(acc3)};
      *(bf16x4*)&rY[n * RY_N + wid * RY_H + lane * 4] = y4;
    }
    if (n < 15) {  // write X_{n+1}
#pragma unroll
      for (int p = 0; p < 4; ++p) {
        int i = p * 512 + tid;
        bf16x4 o4 = {f2b(xr[p].x), f2b(xr[p].y), f2b(xr[p].z), f2b(xr[p].w)};
        *(bf16x4*)&Xb[cur ^ 1][i >> 6][(i & 63) * 4] = o4;
      }
    }
    __syncthreads();  // Xb[cur^1] ready; y writes visible for phase 2
  }

  // ---- phase 2: o = y @ wvT per head (wave = head), fused gate ----
  {
    const int lr = lane & 15, kg = lane >> 4;
    vf4 acc[4] = {};
#pragma unroll
    for (int k8 = 0; k8 < 8; ++k8) {
      bf16x8 afr = *(const bf16x8*)&rY[lr * RY_N + wid * RY_H + k8 * 32 + kg * 8];
#pragma unroll
      for (int ct = 0; ct < 4; ++ct) {
        bf16x8 bfr = *(const bf16x8*)&wvT[(size_t)(wid * 64 + ct * 16 + lr) * 256 +
                                          k8 * 32 + kg * 8];
        acc[ct] = __builtin_amdgcn_mfma_f32_16x16x32_bf16(afr, bfr, acc[ct], 0, 0, 0);
      }
    }
#pragma unroll
    for (int ct = 0; ct < 4; ++ct)
#pragma unroll
      for (int j = 0; j < 4; ++j) {
        int row = kg * 4 + j;
        int col = wid * 64 + ct * 16 + lr;
        oS[0][row * 536 + col] = f2b(acc[ct][j] * (float)gS[row][col]);
      }
  }
  __syncthreads();

  // ---- phase 3: out = oS @ woT + bo (wave w: col tiles 2w, 2w+1) ----
  {
    const int lr = lane & 15, kg = lane >> 4;
    vf4 acc[2] = {};
#pragma unroll
    for (int k8 = 0; k8 < 16; ++k8) {
      bf16x8 afr = *(const bf16x8*)&oS[0][lr * 536 + k8 * 32 + kg * 8];
#pragma unroll
      for (int cc = 0; cc < 2; ++cc) {
        int cb = (wid * 2 + cc) * 16;
        bf16x8 bfr =
            *(const bf16x8*)&woT[(size_t)(cb + lr) * 512 + k8 * 32 + kg * 8];
        acc[cc] = __builtin_amdgcn_mfma_f32_16x16x32_bf16(afr, bfr, acc[cc], 0, 0, 0);
      }
    }
#pragma unroll
    for (int cc = 0; cc < 2; ++cc) {
      const int col = (wid * 2 + cc) * 16 + lr;
      const float bov = bo[col];
#pragma unroll
      for (int j = 0; j < 4; ++j) {
        int row = kg * 4 + j;
        out[(size_t)(bn0 + row) * 256 + col] = acc[cc][j] + bov;
      }
    }
  }
}

}  // namespace

extern "C" void kernel_launch(void* const* d_in, const int* in_sizes, int n_in,
                              void* d_out, int out_size, void* d_ws,
                              size_t ws_size, hipStream_t stream) {
  const float* t = (const float*)d_in[0];
  const float* s = (const float*)d_in[1];
  const float* msk = (const float*)d_in[2];
  const float* wq = (const float*)d_in[3];
  const float* wk = (const float*)d_in[4];
  const float* wv = (const float*)d_in[5];
  const float* wg = (const float*)d_in[6];
  const float* bg = (const float*)d_in[7];
  const float* wo = (const float*)d_in[8];
  const float* bo = (const float*)d_in[9];
  float* out = (float*)d_out;

  char* p = (char*)d_ws;
  __bf16* Qbf = (__bf16*)p;   p += (size_t)BN * 512 * 2;   // 4 MB
  __bf16* Gbf = (__bf16*)p;   p += (size_t)BN * 512 * 2;   // 4 MB
  __bf16* Rbf = (__bf16*)p;   p += (size_t)BN * 2048 * 2;  // 16 MB
  __bf16* wqT = (__bf16*)p;   p += 512 * 256 * 2;
  __bf16* wgT = (__bf16*)p;   p += 512 * 256 * 2;
  __bf16* wvT = (__bf16*)p;   p += 512 * 256 * 2;
  __bf16* woT = (__bf16*)p;   p += 256 * 512 * 2;
  __bf16* wkbf = (__bf16*)p;  p += 256 * 512 * 2;

  k_cvtW<<<640, 256, 0, stream>>>(wq, wg, wk, wv, wo, wqT, wgT, wkbf, wvT, woT);
  k_qg<<<dim3(BN / 64, 16), 256, 0, stream>>>(s, wqT, wgT, bg, Qbf, Gbf);
  k_r<<<dim3(BN / 64, 32), 256, 0, stream>>>(Qbf, wkbf, Rbf);
  k_main<<<256, 512, 0, stream>>>(t, msk, Rbf, Gbf, wvT, woT, bo, out);
}